// Round 3
// baseline (339.489 us; speedup 1.0000x reference)
//
#include <hip/hip_runtime.h>

// VQ-VAE EMA vector quantizer, fp32 in/out.
// N=65536 rows (32*2048), D=256, K=1024 codes.
//
// R8: distance GEMM on matrix cores via double-f16 split (3x mfma per K32):
//     128*z = zh+zl, 128*e = eh+el; acc = zh*eh + zh*el + zl*eh (fp32 acc).
//     Exact power-of-2 descale in the fold: d = fmaf(acc,-0x1p-13f,zsq)+esq.
// R9: flat K'=768, 256x128 tile, tri-buffered LDS, counted vmcnt(6).
//     143 -> 142 us but profile moved: HBM 46% (A panel restaged 8x = 512 MB),
//     LDS-read ~45%, MFMA 31% -- three pipes each half-busy.
// R10: restructure so each operand uses its cheapest path:
//     - B (codebook, 1 MB, L2-resident) pre-laid FRAGMENT-MAJOR by vq_prep_e:
//       a wave's B-frag load = one coalesced 1KB global_load_dwordx4 ->
//       B bypasses LDS entirely (no ds_write/ds_read, no staging barrier).
//     - A staged in LDS (8 KB/K-step, 1 global_load_lds per thread),
//       tri-buffered, single barrier + counted vmcnt(9) per K-step
//       (9 = 8 B-loads + 1 A-stage issued per iter; in-order retirement).
//     - block = 128 rows x 1024 codes in 2 col-passes of 512 (acc 128 VGPR);
//       A read once per pass instead of 8x -> A traffic 512 -> ~96-128 MB.
//     - argmin fold via 16-lane shfl butterfly (frees 32 persistent VGPR),
//       zsq from LDS.

#define DDIM 256
#define DQ   64
#define KC   1024
#define NROW 65536
#define BM   128     // fp32-fallback tile
#define BN   128
#define BD   32
#define LS   34
#define DECAYF 0.99f
#define OMDF   0.01f
#define BETAF  0.25f
#define EPSF   1e-5f

// R10 mfma geometry
#define BMR  128     // rows per block
#define NIT  48      // 2 passes x 24 K-blocks of 32

typedef _Float16 f16;
typedef _Float16 f16x8 __attribute__((ext_vector_type(8)));
typedef float    f32x4 __attribute__((ext_vector_type(4)));

__device__ __forceinline__ void gl_lds16(const f16* g, f16* l) {
    __builtin_amdgcn_global_load_lds(
        (const __attribute__((address_space(1))) void*)g,
        (__attribute__((address_space(3))) void*)l, 16, 0, 0);
}

// one-shot ||e||^2 (fallback path only; mfma path gets esq from vq_prep_e)
__global__ __launch_bounds__(256) void vq_esq(const float* __restrict__ emb,
                                              float* __restrict__ esq_g)
{
    int k = blockIdx.x * 256 + threadIdx.x;
    const float4* ep = (const float4*)(emb + (size_t)k * DDIM);
    float s = 0.f;
    for (int q = 0; q < DQ; ++q) {
        float4 v = ep[q];
        s += v.x * v.x + v.y * v.y + v.z * v.z + v.w * v.w;
    }
    esq_g[k] = s;
}

// f32 -> double-f16 split, plane layout [row][zh(256) | zl(256)] f16.
// Also emits ||x||^2 per row (8-elem partials + 32-lane shfl tree).
__global__ __launch_bounds__(256) void vq_prep(const float* __restrict__ src,
                                               f16* __restrict__ dst,
                                               float* __restrict__ sq_g)
{
    int t   = blockIdx.x * 256 + threadIdx.x;   // 8-elem chunk id
    int row = t >> 5;                           // 32 chunks per row
    int c   = t & 31;
    const float4* sp = (const float4*)(src + (size_t)row * DDIM + c * 8);
    float4 v0 = sp[0], v1 = sp[1];
    float x[8] = {v0.x, v0.y, v0.z, v0.w, v1.x, v1.y, v1.z, v1.w};
    f16x8 h, l;
    float s = 0.f;
#pragma unroll
    for (int j = 0; j < 8; ++j) {
        float xs = x[j] * 128.0f;
        f16 hh = (f16)xs;
        h[j] = hh;
        l[j] = (f16)(xs - (float)hh);
        s += x[j] * x[j];
    }
    f16* rp = dst + (size_t)row * 512;
    *(f16x8*)(rp + c * 8)       = h;
    *(f16x8*)(rp + 256 + c * 8) = l;
    s += __shfl_xor(s, 1);
    s += __shfl_xor(s, 2);
    s += __shfl_xor(s, 4);
    s += __shfl_xor(s, 8);
    s += __shfl_xor(s, 16);
    if (c == 0) sq_g[row] = s;
}

// Codebook -> fragment-major f16 split.
// Layout: ehl2[plane(2)][kb(8)][cg(64)][lane(64)][8 f16]; a wave's B-frag
// load for (plane,kb,cg) is base + lane*16B -> one coalesced 1KB load.
// lane = kg*16 + (code&15), holding e[code = cg*16 + (lane&15)]
//                                    [k = kb*32 + (lane>>4)*8 .. +7].
__global__ __launch_bounds__(256) void vq_prep_e(const float* __restrict__ emb,
                                                 f16* __restrict__ ehl2,
                                                 float* __restrict__ esq_g)
{
    int t     = blockIdx.x * 256 + threadIdx.x;
    int c     = t >> 5;          // code
    int chunk = t & 31;          // k0 = chunk*8
    const float4* sp = (const float4*)(emb + (size_t)c * DDIM + chunk * 8);
    float4 v0 = sp[0], v1 = sp[1];
    float x[8] = {v0.x, v0.y, v0.z, v0.w, v1.x, v1.y, v1.z, v1.w};
    f16x8 h, l;
    float s = 0.f;
#pragma unroll
    for (int j = 0; j < 8; ++j) {
        float xs = x[j] * 128.0f;
        f16 hh = (f16)xs;
        h[j] = hh;
        l[j] = (f16)(xs - (float)hh);
        s += x[j] * x[j];
    }
    int kb = chunk >> 2, kg = chunk & 3;
    int cg = c >> 4;
    int lanep = kg * 16 + (c & 15);
    size_t idx = ((size_t)(kb * 64 + cg)) * 512 + lanep * 8;
    *(f16x8*)(ehl2 + idx)          = h;          // plane 0 (eh)
    *(f16x8*)(ehl2 + 262144 + idx) = l;          // plane 1 (el)
    s += __shfl_xor(s, 1);
    s += __shfl_xor(s, 2);
    s += __shfl_xor(s, 4);
    s += __shfl_xor(s, 8);
    s += __shfl_xor(s, 16);
    if (chunk == 0) esq_g[c] = s;
}

// ---- R10 main kernel ----
// 512 blocks x 512 thr (8 waves: wr=wave>>2 in {0,1} rows, wc=wave&3 cols).
// Wave tile 64 rows x 128 cols; acc[4][8] f32x4 = 128 VGPR.
// it = 0..47: pass p = it/24 (cols p*512..), kb = it%24 over flat K'=768
//   (kb 0-7: zh*eh, 8-15: zh*el, 16-23: zl*eh).

#define FOLD(P) do {                                                        \
    _Pragma("unroll")                                                       \
    for (int i_ = 0; i_ < 4; ++i_) {                                        \
      _Pragma("unroll")                                                     \
      for (int t_ = 0; t_ < 4; ++t_) {                                      \
        int row_ = wr * 64 + i_ * 16 + kg * 4 + t_;                         \
        float zq2_ = zsq_s[row_];                                           \
        float bv_ = 3.4e38f; int bix_ = 0;                                  \
        _Pragma("unroll")                                                   \
        for (int j_ = 0; j_ < 8; ++j_) {                                    \
          int col_ = (P) * 512 + wc * 128 + j_ * 16 + c16;                  \
          float d_ = fmaf(acc[i_][j_][t_], -0x1p-13f, zq2_) + esq_s[col_];  \
          if (d_ < bv_) { bv_ = d_; bix_ = col_; }                          \
        }                                                                   \
        _Pragma("unroll")                                                   \
        for (int m_ = 1; m_ < 16; m_ <<= 1) {                               \
          float ov_ = __shfl_xor(bv_, m_);                                  \
          int   oi_ = __shfl_xor(bix_, m_);                                 \
          if (ov_ < bv_ || (ov_ == bv_ && oi_ < bix_)) { bv_ = ov_; bix_ = oi_; } \
        }                                                                   \
        if (c16 == 0) {                                                     \
          red_v2[row_ * 8 + (P) * 4 + wc] = bv_;                            \
          red_i2[row_ * 8 + (P) * 4 + wc] = bix_;                           \
        }                                                                   \
      }                                                                     \
    }                                                                       \
    _Pragma("unroll")                                                       \
    for (int i_ = 0; i_ < 4; ++i_)                                          \
      _Pragma("unroll")                                                     \
      for (int j_ = 0; j_ < 8; ++j_) acc[i_][j_] = zero4;                   \
} while (0)

#define BODY(IT, BC, BN_) do {                                              \
    asm volatile("s_waitcnt vmcnt(9)" ::: "memory");                        \
    __builtin_amdgcn_s_barrier();                                           \
    const f16* Ab_ = &Abuf[(IT) % 3][0];                                    \
    f16x8 af0 = *(const f16x8*)(Ab_ + ((wr4 + 0) * 64 + lane) * 8);         \
    f16x8 af1 = *(const f16x8*)(Ab_ + ((wr4 + 1) * 64 + lane) * 8);         \
    f16x8 af2 = *(const f16x8*)(Ab_ + ((wr4 + 2) * 64 + lane) * 8);         \
    f16x8 af3 = *(const f16x8*)(Ab_ + ((wr4 + 3) * 64 + lane) * 8);         \
    { /* B-frag loads for IT+1 (global -> regs, L2-resident, coalesced) */  \
      int itn_ = (IT) + 1; if (itn_ > NIT - 1) itn_ = NIT - 1;              \
      int kbn_ = itn_ % 24; int pn_ = itn_ / 24;                            \
      int bpl_ = (kbn_ >= 8 && kbn_ < 16) ? 1 : 0;                          \
      const f16* bp_ = ehl2 + (((size_t)((bpl_ * 8 + (kbn_ & 7)) * 64       \
                        + pn_ * 32 + wc8)) << 9) + lane * 8;                \
      _Pragma("unroll")                                                     \
      for (int j_ = 0; j_ < 8; ++j_)                                        \
          BN_[j_] = *(const f16x8*)(bp_ + j_ * 512);                        \
    }                                                                       \
    { /* A stage for IT+2 (global_load_lds, 1 op/thread) */                 \
      int its_ = (IT) + 2;                                                  \
      int bs_ = its_ % 3;                                                   \
      if (its_ > NIT - 1) its_ = NIT - 1;                                   \
      int kbs_ = its_ % 24;                                                 \
      int aoff_ = ((kbs_ & 16) ? 256 : 0) + (kbs_ & 7) * 32;                \
      gl_lds16(astage + aoff_, &Abuf[bs_][0] + (size_t)tid * 8);            \
    }                                                                       \
    __builtin_amdgcn_s_setprio(1);                                          \
    _Pragma("unroll")                                                       \
    for (int j_ = 0; j_ < 8; ++j_) {                                        \
        acc[0][j_] = __builtin_amdgcn_mfma_f32_16x16x32_f16(af0, BC[j_], acc[0][j_], 0, 0, 0); \
        acc[1][j_] = __builtin_amdgcn_mfma_f32_16x16x32_f16(af1, BC[j_], acc[1][j_], 0, 0, 0); \
        acc[2][j_] = __builtin_amdgcn_mfma_f32_16x16x32_f16(af2, BC[j_], acc[2][j_], 0, 0, 0); \
        acc[3][j_] = __builtin_amdgcn_mfma_f32_16x16x32_f16(af3, BC[j_], acc[3][j_], 0, 0, 0); \
    }                                                                       \
    __builtin_amdgcn_s_setprio(0);                                          \
    if (((IT) % 24) == 23) { FOLD((IT) / 24); }                             \
} while (0)

__global__ __launch_bounds__(512) void vq_main_mfma(
    const float* __restrict__ z,         // [N, D] f32 (epilogue)
    const float* __restrict__ emb,       // [K, D] f32 (epilogue gather)
    const f16*  __restrict__ zhl,        // [N][zh 256 | zl 256] f16
    const f16*  __restrict__ ehl2,       // fragment-major codebook (1 MB)
    const float* __restrict__ esq_g,     // [K]
    const float* __restrict__ zsq_g,     // [N]
    float* __restrict__ out_zq,
    float* __restrict__ out_codes,
    float* __restrict__ loss_acc)
{
    __shared__ f16   Abuf[3][4096];      // 3 x 8 KB A tri-buffer
    __shared__ float esq_s[KC];          // 4 KB
    __shared__ float zsq_s[BMR];         // 512 B
    __shared__ float red_v2[BMR * 8];    // 4 KB
    __shared__ int   red_i2[BMR * 8];    // 4 KB
    __shared__ int   codes_s[BMR];
    __shared__ float lred[512];

    const int tid  = threadIdx.x;
    const int row0 = blockIdx.x * BMR;
    const int wave = tid >> 6, lane = tid & 63;
    const int wr   = wave >> 2, wc = wave & 3;   // 2M x 4N wave grid
    const int wr4  = wr * 4;
    const int wc8  = wc * 8;
    const int kg   = lane >> 4, c16 = lane & 15;

    // ---- prologue ----
    { float2 v = ((const float2*)esq_g)[tid];
      *(float2*)(esq_s + tid * 2) = v; }
    if (tid < BMR) zsq_s[tid] = zsq_g[row0 + tid];

    // A-stage source descriptor: thread t stages LDS bytes [t*16, t*16+16)
    // = row (t>>6)*16 + (t&15), k-chunk ((t>>4)&3)*8 of the 32-K slice.
    const f16* astage = zhl + (size_t)(row0 + (tid >> 6) * 16 + (tid & 15)) * 512
                            + ((tid >> 4) & 3) * 8;

    f16x8 bA[8], bB[8];
    // stage A(0), A(1); load B(0)
    gl_lds16(astage + 0,  &Abuf[0][0] + (size_t)tid * 8);   // kb=0: zh chunk 0
    gl_lds16(astage + 32, &Abuf[1][0] + (size_t)tid * 8);   // kb=1: zh chunk 1
    {
        const f16* bp = ehl2 + ((size_t)wc8 << 9) + lane * 8;  // plane 0, kb 0, p 0
#pragma unroll
        for (int j = 0; j < 8; ++j) bA[j] = *(const f16x8*)(bp + j * 512);
    }
    asm volatile("s_waitcnt lgkmcnt(0)" ::: "memory");      // esq/zsq ds_writes

    f32x4 acc[4][8];
    const f32x4 zero4 = {0.f, 0.f, 0.f, 0.f};
#pragma unroll
    for (int i = 0; i < 4; ++i)
#pragma unroll
        for (int j = 0; j < 8; ++j) acc[i][j] = zero4;

#pragma unroll 1
    for (int it = 0; it < NIT; it += 2) {
        BODY(it,     bA, bB);
        BODY(it + 1, bB, bA);
    }

    // ---- final argmin scan: 8 candidates/row (pass x wc), asc col order ----
    __syncthreads();
    if (tid < BMR) {
        float bv = red_v2[tid * 8];
        int   bi = red_i2[tid * 8];
#pragma unroll
        for (int t = 1; t < 8; ++t) {
            float v  = red_v2[tid * 8 + t];
            int   ix = red_i2[tid * 8 + t];
            if (v < bv || (v == bv && ix < bi)) { bv = v; bi = ix; }
        }
        codes_s[tid] = bi;
        out_codes[row0 + tid] = (float)bi;
    }
    __syncthreads();

    // ---- epilogue: gather z_q (exact f32), write z_q_st, loss partial ----
    float lp = 0.f;
#pragma unroll 1
    for (int r = wave; r < BMR; r += 8) {
        int code = codes_s[r];
        float4 e4 = *(const float4*)(emb + (size_t)code * DDIM + lane * 4);
        float4 z4 = *(const float4*)(z + (size_t)(row0 + r) * DDIM + lane * 4);
        float dx = e4.x - z4.x, dy = e4.y - z4.y, dz = e4.z - z4.z, dw = e4.w - z4.w;
        float4 o;
        o.x = z4.x + dx; o.y = z4.y + dy; o.z = z4.z + dz; o.w = z4.w + dw;
        *(float4*)(out_zq + (size_t)(row0 + r) * DDIM + lane * 4) = o;
        lp += dx * dx + dy * dy + dz * dz + dw * dw;
    }
    lred[tid] = lp;
    __syncthreads();
    for (int st = 256; st > 0; st >>= 1) {
        if (tid < st) lred[tid] += lred[tid + st];
        __syncthreads();
    }
    if (tid == 0) atomicAdd(loss_acc, lred[0]);
}

// ---------- R7 fp32 kernel, kept verbatim as ws_size fallback ----------
__global__ __launch_bounds__(256) void vq_main_f32(
    const float* __restrict__ z,
    const float* __restrict__ emb,
    const float* __restrict__ esq_g,
    float* __restrict__ out_zq,
    float* __restrict__ out_codes,
    float* __restrict__ loss_acc)
{
    __shared__ float zs[BM * LS];
    __shared__ float es[BN * LS];
    __shared__ float esq_s[KC];
    __shared__ float zsq_s[BM];
    float* red_v   = zs;
    int*   red_i   = (int*)(zs + 2048);
    int*   codes_s = (int*)es;
    float* lred    = es + 128;

    const int tid  = threadIdx.x;
    const int row0 = blockIdx.x * BM;
    const int trow = tid >> 4;
    const int tcol = tid & 15;

    {
        const float4* eg = (const float4*)esq_g;
        float4 v = eg[tid];
        *(float4*)(esq_s + tid * 4) = v;
    }
    if (tid < BM) {
        const float4* zp = (const float4*)(z + (size_t)(row0 + tid) * DDIM);
        float s = 0.f;
        for (int q = 0; q < DQ; ++q) {
            float4 v = zp[q];
            s += v.x * v.x + v.y * v.y + v.z * v.z + v.w * v.w;
        }
        zsq_s[tid] = s;
    }

    const int r0 = tid >> 3;
    const int q0 = tid & 7;
    const float* zp0 = z + (size_t)(row0 + r0) * DDIM + q0 * 4;
    const float* ep0 = emb + (size_t)r0 * DDIM + q0 * 4;
    const int ls0 = r0 * LS + q0 * 4;

    float4 pz[4], pe[4];
#pragma unroll
    for (int it = 0; it < 4; ++it) {
        pz[it] = *(const float4*)(zp0 + it * 32 * DDIM);
        pe[it] = *(const float4*)(ep0 + it * 32 * DDIM);
    }

    float runv[8];
    int   runi[8];
#pragma unroll
    for (int i = 0; i < 8; ++i) { runv[i] = 3.4e38f; runi[i] = 0; }

#pragma unroll 1
    for (int kt = 0; kt < KC / BN; ++kt) {
        float acc[8][8];
#pragma unroll
        for (int i = 0; i < 8; ++i)
#pragma unroll
            for (int j = 0; j < 8; ++j) acc[i][j] = 0.f;

#pragma unroll 1
        for (int dc = 0; dc < DDIM / BD; ++dc) {
            __syncthreads();
#pragma unroll
            for (int it = 0; it < 4; ++it) {
                int o = ls0 + it * 32 * LS;
                *(float2*)(zs + o)     = make_float2(pz[it].x, pz[it].y);
                *(float2*)(zs + o + 2) = make_float2(pz[it].z, pz[it].w);
                *(float2*)(es + o)     = make_float2(pe[it].x, pe[it].y);
                *(float2*)(es + o + 2) = make_float2(pe[it].z, pe[it].w);
            }
            __syncthreads();
            {
                int ndc = dc + 1, nkt = kt;
                if (ndc == DDIM / BD) { ndc = 0; ++nkt; }
                if (nkt < KC / BN) {
                    size_t zo = (size_t)ndc * BD;
                    size_t eo = (size_t)nkt * BN * DDIM + (size_t)ndc * BD;
#pragma unroll
                    for (int it = 0; it < 4; ++it) {
                        pz[it] = *(const float4*)(zp0 + it * 32 * DDIM + zo);
                        pe[it] = *(const float4*)(ep0 + it * 32 * DDIM + eo);
                    }
                }
            }
#pragma unroll
            for (int s = 0; s < BD / 2; ++s) {
                float2 a2[8], b2[8];
#pragma unroll
                for (int i = 0; i < 8; ++i)
                    a2[i] = *(const float2*)(zs + (trow + 16 * i) * LS + s * 2);
#pragma unroll
                for (int j = 0; j < 8; ++j)
                    b2[j] = *(const float2*)(es + (tcol + 16 * j) * LS + s * 2);
#pragma unroll
                for (int i = 0; i < 8; ++i)
#pragma unroll
                    for (int j = 0; j < 8; ++j)
                        acc[i][j] = fmaf(a2[i].y, b2[j].y,
                                     fmaf(a2[i].x, b2[j].x, acc[i][j]));
            }
        }
#pragma unroll
        for (int i = 0; i < 8; ++i) {
            float zq2 = zsq_s[trow + 16 * i];
#pragma unroll
            for (int j = 0; j < 8; ++j) {
                int col = kt * BN + tcol + 16 * j;
                float dist = zq2 - 2.f * acc[i][j] + esq_s[col];
                if (dist < runv[i]) { runv[i] = dist; runi[i] = col; }
            }
        }
    }

    __syncthreads();
#pragma unroll
    for (int i = 0; i < 8; ++i) {
        int lr = trow + 16 * i;
        red_v[lr * 16 + tcol] = runv[i];
        red_i[lr * 16 + tcol] = runi[i];
    }
    __syncthreads();
    if (tid < BM) {
        float bv = red_v[tid * 16];
        int   bi = red_i[tid * 16];
        for (int t = 1; t < 16; ++t) {
            float v  = red_v[tid * 16 + t];
            int   ix = red_i[tid * 16 + t];
            if (v < bv || (v == bv && ix < bi)) { bv = v; bi = ix; }
        }
        codes_s[tid] = bi;
        out_codes[row0 + tid] = (float)bi;
    }
    __syncthreads();

    const int wavf = tid >> 6;
    const int lanf = tid & 63;
    float lp = 0.f;
    for (int r = wavf; r < BM; r += 4) {
        int code = codes_s[r];
        float4 e4 = *(const float4*)(emb + (size_t)code * DDIM + lanf * 4);
        float4 z4 = *(const float4*)(z + (size_t)(row0 + r) * DDIM + lanf * 4);
        float dx = e4.x - z4.x, dy = e4.y - z4.y, dz = e4.z - z4.z, dw = e4.w - z4.w;
        float4 o;
        o.x = z4.x + dx; o.y = z4.y + dy; o.z = z4.z + dz; o.w = z4.w + dw;
        *(float4*)(out_zq + (size_t)(row0 + r) * DDIM + lanf * 4) = o;
        lp += dx * dx + dy * dy + dz * dz + dw * dw;
    }
    lred[tid] = lp;
    __syncthreads();
    for (int s = 128; s > 0; s >>= 1) {
        if (tid < s) lred[tid] += lred[tid + s];
        __syncthreads();
    }
    if (tid == 0) atomicAdd(loss_acc, lred[0]);
}

// One block per code k; scan codes (L2-resident), gather rows coalesced.
__global__ __launch_bounds__(256) void vq_scatter(
    const float* __restrict__ z,
    const float* __restrict__ codes_f,
    float* __restrict__ embed_sum,
    float* __restrict__ counts)
{
    __shared__ int list[1024];
    __shared__ int nmatch;
    const int k   = blockIdx.x;
    const int tid = threadIdx.x;

    float acc = 0.f;
    int total = 0;
    if (tid == 0) nmatch = 0;
    __syncthreads();

    for (int base = 0; base < NROW; base += 1024) {
        float4 c4 = *(const float4*)(codes_f + base + tid * 4);
        int i0 = base + tid * 4;
        if ((int)c4.x == k) { int p = atomicAdd(&nmatch, 1); list[p] = i0; }
        if ((int)c4.y == k) { int p = atomicAdd(&nmatch, 1); list[p] = i0 + 1; }
        if ((int)c4.z == k) { int p = atomicAdd(&nmatch, 1); list[p] = i0 + 2; }
        if ((int)c4.w == k) { int p = atomicAdd(&nmatch, 1); list[p] = i0 + 3; }
        __syncthreads();
        int nm = nmatch;
        for (int i = 0; i < nm; ++i)
            acc += z[(size_t)list[i] * DDIM + tid];
        total += nm;
        __syncthreads();
        if (tid == 0) nmatch = 0;
        __syncthreads();
    }
    embed_sum[(size_t)k * DDIM + tid] = acc;
    if (tid == 0) counts[k] = (float)total;
}

__global__ void vq_finalize(const float* __restrict__ cluster_size,
                            const float* __restrict__ counts,
                            const float* __restrict__ loss_acc,
                            float* __restrict__ out_ncs,
                            float* __restrict__ out_loss,
                            float* __restrict__ cs_sm,
                            float inv_ND)
{
    __shared__ float sred[KC];
    const int tid = threadIdx.x;
    float ncs = cluster_size[tid] * DECAYF + counts[tid] * OMDF;
    out_ncs[tid] = ncs;
    sred[tid] = ncs;
    __syncthreads();
    for (int s = KC / 2; s > 0; s >>= 1) {
        if (tid < s) sred[tid] += sred[tid + s];
        __syncthreads();
    }
    float n = sred[0];
    cs_sm[tid] = (ncs + EPSF) / (n + (float)KC * EPSF) * n;
    if (tid == 0) out_loss[0] = BETAF * loss_acc[0] * inv_ND;
}

__global__ void vq_embed(const float* __restrict__ embed_avg,
                         const float* __restrict__ embed_sum,
                         const float* __restrict__ cs_sm,
                         float* __restrict__ out_nea,
                         float* __restrict__ out_nemb)
{
    int idx = blockIdx.x * blockDim.x + threadIdx.x;
    int k = idx >> 6;
    float4 ea = ((const float4*)embed_avg)[idx];
    float4 s4 = ((const float4*)embed_sum)[idx];
    float4 nea;
    nea.x = ea.x * DECAYF + s4.x * OMDF;
    nea.y = ea.y * DECAYF + s4.y * OMDF;
    nea.z = ea.z * DECAYF + s4.z * OMDF;
    nea.w = ea.w * DECAYF + s4.w * OMDF;
    ((float4*)out_nea)[idx] = nea;
    float cs = cs_sm[k];
    float4 ne;
    ne.x = nea.x / cs; ne.y = nea.y / cs; ne.z = nea.z / cs; ne.w = nea.w / cs;
    ((float4*)out_nemb)[idx] = ne;
}

extern "C" void kernel_launch(void* const* d_in, const int* in_sizes, int n_in,
                              void* d_out, int out_size, void* d_ws, size_t ws_size,
                              hipStream_t stream) {
    const float* z            = (const float*)d_in[0];   // [N, 256]
    const float* emb          = (const float*)d_in[1];   // [1024, 256]
    const float* cluster_size = (const float*)d_in[2];   // [1024]
    const float* embed_avg    = (const float*)d_in[3];   // [1024, 256]

    const int ND = in_sizes[0];       // N*D = 16777216
    const int KD = in_sizes[1];       // K*D = 262144
    const int K  = in_sizes[2];       // 1024
    const int N  = ND / DDIM;         // 65536

    float* out       = (float*)d_out;
    float* out_zq    = out;
    float* out_loss  = out + (size_t)ND;
    float* out_codes = out + (size_t)ND + 1;
    float* out_nemb  = out + (size_t)ND + 1 + N;
    float* out_ncs   = out_nemb + (size_t)KD;
    float* out_nea   = out_ncs + (size_t)K;

    float* ws        = (float*)d_ws;
    float* loss_acc  = ws;                 // [1]
    float* counts    = ws + 1;             // [K]
    float* cs_sm     = counts + K;         // [K]
    float* esq_g     = cs_sm + K;          // [K]
    float* zsq_g     = esq_g + K;          // [N]
    float* embed_sum = zsq_g + N;          // [K*D]

    size_t base_floats = (size_t)1 + 3 * (size_t)K + (size_t)N + (size_t)KD;
    size_t f16_off = (base_floats * sizeof(float) + 255) & ~(size_t)255;
    size_t zbytes  = (size_t)N * 512 * sizeof(f16);      // 64 MB
    size_t ebytes  = (size_t)2 * 262144 * sizeof(f16);   // 1 MB fragment-major
    bool mfma_ok   = ws_size >= f16_off + zbytes + ebytes;

    hipMemsetAsync(loss_acc, 0, sizeof(float), stream);
    if (mfma_ok) {
        f16* zhl  = (f16*)((char*)d_ws + f16_off);
        f16* ehl2 = (f16*)((char*)d_ws + f16_off + zbytes);
        vq_prep<<<(N * 32) / 256, 256, 0, stream>>>(z, zhl, zsq_g);
        vq_prep_e<<<(K * 32) / 256, 256, 0, stream>>>(emb, ehl2, esq_g);
        vq_main_mfma<<<N / BMR, 512, 0, stream>>>(
            z, emb, zhl, ehl2, esq_g, zsq_g, out_zq, out_codes, loss_acc);
    } else {
        vq_esq<<<K / 256, 256, 0, stream>>>(emb, esq_g);
        vq_main_f32<<<N / BM, 256, 0, stream>>>(z, emb, esq_g,
                                                out_zq, out_codes, loss_acc);
    }
    vq_scatter<<<K, 256, 0, stream>>>(z, out_codes, embed_sum, counts);
    vq_finalize<<<1, K, 0, stream>>>(cluster_size, counts, loss_acc,
                                     out_ncs, out_loss, cs_sm, 1.0f / (float)ND);
    vq_embed<<<KD / 1024, 256, 0, stream>>>(embed_avg, embed_sum, cs_sm,
                                            out_nea, out_nemb);
}